// Round 2
// baseline (13.740 us; speedup 1.0000x reference)
//
#include <hip/hip_runtime.h>

// out[n,c,h,w] = sum over valid (i,j) in 3x3 of max(x[n,c,h,w], thr[c, 3*i+j])
// valid: i=0 iff h<111, i=1 always, i=2 iff h>0; j likewise vs w.
// (unfold->max->fold collapses to elementwise; see analysis)

#define NH 112
#define NW 112
#define WQ 28          // NW / 4 (float4 per row)
#define ROW_SPLIT 4
#define ROWS_PER_BLK 28

__global__ __launch_bounds__(256) void convblock_elem_kernel(
    const float* __restrict__ x, const float* __restrict__ thr,
    float* __restrict__ out) {
  const int blk = blockIdx.x;
  const int plane = blk / ROW_SPLIT;   // n*64 + c
  const int chunk = blk - plane * ROW_SPLIT;
  const int c = plane & 63;

  float t[9];
#pragma unroll
  for (int k = 0; k < 9; ++k) t[k] = thr[c * 9 + k];

  const float4* __restrict__ xin =
      reinterpret_cast<const float4*>(x) + (size_t)plane * (NH * WQ);
  float4* __restrict__ xout =
      reinterpret_cast<float4*>(out) + (size_t)plane * (NH * WQ);
  const int r0 = chunk * ROWS_PER_BLK;

  for (int idx = threadIdx.x; idx < ROWS_PER_BLK * WQ; idx += 256) {
    const int hr = idx / WQ;
    const int wq = idx - hr * WQ;
    const int h = r0 + hr;

    const float4 v4 = xin[h * WQ + wq];
    const bool rowTop = (h < NH - 1);  // i=0 included
    const bool rowBot = (h > 0);       // i=2 included

    float vv[4] = {v4.x, v4.y, v4.z, v4.w};
    float res[4];
#pragma unroll
    for (int e = 0; e < 4; ++e) {
      const int w = wq * 4 + e;
      const float v = vv[e];
      float s = 0.0f;
#pragma unroll
      for (int i = 0; i < 3; ++i) {
        const bool rok = (i == 0) ? rowTop : (i == 2) ? rowBot : true;
        if (rok) {
          float r = fmaxf(v, t[3 * i + 0]) + fmaxf(v, t[3 * i + 1]) +
                    fmaxf(v, t[3 * i + 2]);
          if (w == 0)      r -= fmaxf(v, t[3 * i + 2]);  // j=2 excluded at w==0
          if (w == NW - 1) r -= fmaxf(v, t[3 * i + 0]);  // j=0 excluded at w==111
          s += r;
        }
      }
      res[e] = s;
    }
    xout[h * WQ + wq] = make_float4(res[0], res[1], res[2], res[3]);
  }
}

extern "C" void kernel_launch(void* const* d_in, const int* in_sizes, int n_in,
                              void* d_out, int out_size, void* d_ws, size_t ws_size,
                              hipStream_t stream) {
  const float* x = (const float*)d_in[0];     // (8,64,112,112) f32
  const float* thr = (const float*)d_in[1];   // (64,9) f32
  float* out = (float*)d_out;                 // (8,64,112,112) f32

  const int n_planes = 8 * 64;
  dim3 grid(n_planes * ROW_SPLIT);
  convblock_elem_kernel<<<grid, 256, 0, stream>>>(x, thr, out);
}